// Round 1
// baseline (318.122 us; speedup 1.0000x reference)
//
#include <hip/hip_runtime.h>

#define B_ 32
#define C_ 128
#define H_ 32
#define W_ 32
#define WN 63
#define O_ 512  // 4*C

typedef __attribute__((ext_vector_type(8))) short bf16x8;
typedef __attribute__((ext_vector_type(4))) float f32x4;
typedef __attribute__((ext_vector_type(4))) unsigned short us4;

__device__ __forceinline__ unsigned short f2bf(float f) {
  union { float f; unsigned u; } v; v.f = f;
  unsigned r = v.u + 0x7FFFu + ((v.u >> 16) & 1u);
  return (unsigned short)(r >> 16);
}
__device__ __forceinline__ float bf2f(unsigned short h) {
  union { unsigned u; float f; } v; v.u = ((unsigned)h) << 16;
  return v.f;
}

// ---------------------------------------------------------------------------
// Kernel 1: i_s (x-part only, no bias) = W_is @ x  per (b,j): 512x32, K=128
// store bf16 to is_ws[((b*32+j)*32 + c)*512 + o]
// ---------------------------------------------------------------------------
__global__ __launch_bounds__(512, 2)
void is_kernel(const float* __restrict__ x, const float* __restrict__ W_is,
               unsigned short* __restrict__ is_ws) {
  const int bj = blockIdx.x;
  const int b = bj >> 5, j = bj & 31;
  const int tid = threadIdx.x;
  const int w = tid >> 6, l = tid & 63;
  const int lg = l >> 4, lm = l & 15;

  // xT: rows c (32), cols ch (128) bf16, 16B-chunk swizzled by (c&15)
  __shared__ __align__(16) unsigned short xT[32 * 128];

  {
    const int ch = tid & 127;
    const int cb = tid >> 7;  // 0..3 (block of 8 c's)
    const float* src = x + ((b * C_ + ch) * H_ + j) * W_ + cb * 8;
    f32x4 v0 = *(const f32x4*)(src);
    f32x4 v1 = *(const f32x4*)(src + 4);
    const int byteCol = ch * 2;
#pragma unroll
    for (int i = 0; i < 8; ++i) {
      int c = cb * 8 + i;
      float fv = (i < 4) ? v0[i & 3] : v1[i & 3];
      int addr = c * 256 + (((byteCol >> 4) ^ (c & 15)) << 4) + (byteCol & 15);
      *(unsigned short*)((char*)xT + addr) = f2bf(fv);
    }
  }
  __syncthreads();

  f32x4 acc[4][2];
#pragma unroll
  for (int g = 0; g < 4; ++g)
#pragma unroll
    for (int n = 0; n < 2; ++n) acc[g][n] = (f32x4){0.f, 0.f, 0.f, 0.f};

#pragma unroll
  for (int kf = 0; kf < 4; ++kf) {
    bf16x8 bfv[2];
#pragma unroll
    for (int n = 0; n < 2; ++n) {
      int c = n * 16 + lm;
      int chunk = kf * 4 + lg;
      int addr = c * 256 + ((chunk ^ (c & 15)) << 4);
      bfv[n] = *(const bf16x8*)((const char*)xT + addr);
    }
#pragma unroll
    for (int g = 0; g < 4; ++g) {
      const int o = g * 128 + 16 * w + lm;
      const float* wp = W_is + o * C_ + kf * 32 + lg * 8;
      f32x4 wa = *(const f32x4*)(wp);
      f32x4 wb = *(const f32x4*)(wp + 4);
      bf16x8 af;
      af[0] = (short)f2bf(wa[0]); af[1] = (short)f2bf(wa[1]);
      af[2] = (short)f2bf(wa[2]); af[3] = (short)f2bf(wa[3]);
      af[4] = (short)f2bf(wb[0]); af[5] = (short)f2bf(wb[1]);
      af[6] = (short)f2bf(wb[2]); af[7] = (short)f2bf(wb[3]);
#pragma unroll
      for (int n = 0; n < 2; ++n)
        acc[g][n] = __builtin_amdgcn_mfma_f32_16x16x32_bf16(af, bfv[n], acc[g][n], 0, 0, 0);
    }
  }

#pragma unroll
  for (int g = 0; g < 4; ++g)
#pragma unroll
    for (int n = 0; n < 2; ++n) {
      int c = n * 16 + lm;
      int o = g * 128 + 16 * w + lg * 4;
      us4 st;
#pragma unroll
      for (int r = 0; r < 4; ++r) st[r] = f2bf(acc[g][n][r]);
      *(us4*)(is_ws + ((bj * 32 + c) * O_ + o)) = st;
    }
}

// ---------------------------------------------------------------------------
// Kernel 2: diagonal scan. 32 blocks (one per batch), 512 threads (8 waves).
// Wave w owns channels [16w,16w+16): M-tiles {w, w+8, w+16, w+24} = gates
// o,f,i,g of the same channels -> elementwise is lane-local.
// ---------------------------------------------------------------------------
__global__ __launch_bounds__(512, 2)
void scan_kernel(const float* __restrict__ Wss, const float* __restrict__ b_is,
                 const float* __restrict__ b_ss,
                 const unsigned short* __restrict__ is_ws,
                 float* __restrict__ out) {
  const int b = blockIdx.x;
  const int tid = threadIdx.x;
  const int w = tid >> 6, l = tid & 63;
  const int lg = l >> 4, lm = l & 15;
  const int chW = 16 * w;

  // hT: 33 rows (row 32 = permanent zeros for h_up at j==0) x 128 ch, bf16,
  // 16B-chunk swizzled by (row & 15).
  __shared__ __align__(16) unsigned short hT[33 * 128];
  for (int i = tid; i < 33 * 128; i += 512) hT[i] = 0;

  // Weights in registers: A[g][kf], k = kf*32 + lg*8 + e; kf<4 -> W0 (h_up), kf>=4 -> W1 (h)
  bf16x8 A[4][8];
#pragma unroll
  for (int g = 0; g < 4; ++g) {
    const int o = g * 128 + chW + lm;
#pragma unroll
    for (int kf = 0; kf < 4; ++kf) {
      const int ch = kf * 32 + lg * 8;
      const float* wp = Wss + (o * C_ + ch) * 2;  // interleaved (W0,W1) pairs
      f32x4 q0 = *(const f32x4*)(wp + 0);
      f32x4 q1 = *(const f32x4*)(wp + 4);
      f32x4 q2 = *(const f32x4*)(wp + 8);
      f32x4 q3 = *(const f32x4*)(wp + 12);
      bf16x8 a0, a1;
      a0[0] = (short)f2bf(q0[0]); a1[0] = (short)f2bf(q0[1]);
      a0[1] = (short)f2bf(q0[2]); a1[1] = (short)f2bf(q0[3]);
      a0[2] = (short)f2bf(q1[0]); a1[2] = (short)f2bf(q1[1]);
      a0[3] = (short)f2bf(q1[2]); a1[3] = (short)f2bf(q1[3]);
      a0[4] = (short)f2bf(q2[0]); a1[4] = (short)f2bf(q2[1]);
      a0[5] = (short)f2bf(q2[2]); a1[5] = (short)f2bf(q2[3]);
      a0[6] = (short)f2bf(q3[0]); a1[6] = (short)f2bf(q3[1]);
      a0[7] = (short)f2bf(q3[2]); a1[7] = (short)f2bf(q3[3]);
      A[g][kf] = a0;
      A[g][kf + 4] = a1;
    }
  }

  float bs[4][4];
#pragma unroll
  for (int g = 0; g < 4; ++g)
#pragma unroll
    for (int r = 0; r < 4; ++r) {
      int o = g * 128 + chW + lg * 4 + r;
      bs[g][r] = b_is[o] + b_ss[o];
    }

  float cst[2][4] = {{0.f, 0.f, 0.f, 0.f}, {0.f, 0.f, 0.f, 0.f}};

  __syncthreads();

  for (int t = 0; t < WN; ++t) {
    const int nLo = (t < 47) ? 0 : 1;  // rows j<16 dead once t-31 > 15

    // ---- prefetch i_s for this step (consumed after the MFMA phase) ----
    us4 isv[4][2];
#pragma unroll
    for (int n = 0; n < 2; ++n) {
      if (n >= nLo) {
        const int j = n * 16 + lm;
        const int c = t - j;
        const bool valid = ((unsigned)c < 32u);
        const unsigned short* p =
            is_ws + (((b * 32 + j) * 32 + (valid ? c : 0)) * O_ + chW + lg * 4);
#pragma unroll
        for (int g = 0; g < 4; ++g) {
          if (valid) isv[g][n] = *(const us4*)(p + g * 128);
          else       isv[g][n] = (us4){0, 0, 0, 0};
        }
      }
    }

    // ---- GEMM: z = [W0|W1] @ [h_up; h] ----
    f32x4 acc[4][2];
#pragma unroll
    for (int g = 0; g < 4; ++g)
#pragma unroll
      for (int n = 0; n < 2; ++n) acc[g][n] = (f32x4){0.f, 0.f, 0.f, 0.f};

#pragma unroll
    for (int n = 0; n < 2; ++n) {
      if (n >= nLo) {
        const int j = n * 16 + lm;
        const int rU = (j == 0) ? 32 : j - 1;
#pragma unroll
        for (int kf = 0; kf < 8; ++kf) {
          const int rr = (kf < 4) ? rU : j;
          const int chunk = (kf & 3) * 4 + lg;
          const int addr = rr * 256 + ((chunk ^ (rr & 15)) << 4);
          bf16x8 bfv = *(const bf16x8*)((const char*)hT + addr);
#pragma unroll
          for (int g = 0; g < 4; ++g)
            acc[g][n] = __builtin_amdgcn_mfma_f32_16x16x32_bf16(A[g][kf], bfv, acc[g][n], 0, 0, 0);
        }
      }
    }
    __syncthreads();  // all hT reads done before anyone rewrites hT

    // ---- lane-local LSTM cell + writes ----
#pragma unroll
    for (int n = 0; n < 2; ++n) {
      if (n >= nLo) {
        const int j = n * 16 + lm;
        const int c = t - j;
        const bool inband = ((unsigned)c < 32u);
        unsigned short hb[4];
#pragma unroll
        for (int r = 0; r < 4; ++r) {
          float zo = acc[0][n][r] + bf2f(isv[0][n][r]) + bs[0][r];
          float zf = acc[1][n][r] + bf2f(isv[1][n][r]) + bs[1][r];
          float zi = acc[2][n][r] + bf2f(isv[2][n][r]) + bs[2][r];
          float zg = acc[3][n][r] + bf2f(isv[3][n][r]) + bs[3][r];
          float og = __fdividef(1.f, 1.f + __expf(-zo));
          float fg = __fdividef(1.f, 1.f + __expf(-zf));
          float ig = __fdividef(1.f, 1.f + __expf(-zi));
          float gg = 1.f - __fdividef(2.f, __expf(2.f * zg) + 1.f);
          float cn = fg * cst[n][r] + ig * gg;
          cst[n][r] = cn;
          float th = 1.f - __fdividef(2.f, __expf(2.f * cn) + 1.f);
          float hn = og * th;
          hb[r] = f2bf(hn);
          if (inband)
            out[((b * C_ + (chW + lg * 4 + r)) * H_ + j) * W_ + c] = hn;
        }
        // write h (bf16) back to hT, swizzled
        const int byteCol = chW * 2 + lg * 8;
        const int chunk = byteCol >> 4;
        const int addr = j * 256 + ((chunk ^ (j & 15)) << 4) + (byteCol & 15);
        *(us4*)((char*)hT + addr) = *(us4*)hb;
      }
    }
    __syncthreads();  // hT fully updated before next step's reads
  }
}

// ---------------------------------------------------------------------------
extern "C" void kernel_launch(void* const* d_in, const int* in_sizes, int n_in,
                              void* d_out, int out_size, void* d_ws, size_t ws_size,
                              hipStream_t stream) {
  const float* x    = (const float*)d_in[0];
  const float* W_is = (const float*)d_in[1];
  const float* b_is = (const float*)d_in[2];
  const float* W_ss = (const float*)d_in[3];
  const float* b_ss = (const float*)d_in[4];
  float* out = (float*)d_out;
  unsigned short* is_ws = (unsigned short*)d_ws;  // 32*32*32*512 bf16 = 32 MiB

  is_kernel<<<dim3(B_ * H_), dim3(512), 0, stream>>>(x, W_is, is_ws);
  scan_kernel<<<dim3(B_), dim3(512), 0, stream>>>(W_ss, b_is, b_ss, is_ws, out);
}